// Round 14
// baseline (222.476 us; speedup 1.0000x reference)
//
#include <hip/hip_runtime.h>
#include <hip/hip_fp16.h>

#define N_NODES 100000
#define N_EDGES 1200000
#define D 64
#define N_CLASSES 16
#define NG8  (N_NODES / 8)
#define GRID 2048
#define NXCD 8
#define DRANGE ((N_NODES + NXCD - 1) / NXCD)
#define ESRC_CAP 1900032           // >= E + 7N (pad-8)
#define SENTINEL N_NODES           // index of the all-zero h row
#define NB_CVT 6250
// node-range counting sort
#define NRB 1024
#define RW 98
#define RCAP 2048
#define K1CH 1024
#define K1B ((N_EDGES / 4 + K1CH - 1) / K1CH)   // 293
// chunked h layout: [4][N_NODES+1][16] fp16
#define NCHK 4
#define CHS_H  ((N_NODES + 1) * 16)     // halfs per chunk
#define CHS_U  ((N_NODES + 1) * 8)      // uints per chunk
#define CHS_H2 ((N_NODES + 1) * 8)      // half2 per chunk
#define NBC (N_NODES / 32)              // 3125 node blocks per chunk phase

typedef _Float16 f16x8 __attribute__((ext_vector_type(8)));
typedef float    f32x4 __attribute__((ext_vector_type(4)));

// ============== K1: bin edges into 1024 node-range buckets ================
__global__ __launch_bounds__(256) void bucket_nr_kernel(
        const int* __restrict__ src,
        const int* __restrict__ dst,
        int* __restrict__ bcur,          // [NRB]
        int* __restrict__ bpk) {         // [NRB][RCAP]
    __shared__ int hist[NRB];
    __shared__ int lofs[NRB + 1];
    __shared__ int gbase[NRB];
    __shared__ int tsum[256];
    __shared__ int pk[K1CH * 4];         // 16KB
    int tid = threadIdx.x;
    for (int i = tid; i < NRB; i += 256) hist[i] = 0;
    __syncthreads();

    int c0 = blockIdx.x * K1CH;
    int bn_rk[4][4], pkv[4][4];
#pragma unroll
    for (int it = 0; it < 4; ++it) {
        int c = c0 + it * 256 + tid;
        if (c < N_EDGES / 4) {
            int4 s4 = ((const int4*)src)[c];
            int4 d4 = ((const int4*)dst)[c];
            int ss[4] = {s4.x, s4.y, s4.z, s4.w};
            int dd[4] = {d4.x, d4.y, d4.z, d4.w};
#pragma unroll
            for (int j = 0; j < 4; ++j) {
                int b = dd[j] / RW;
                int rk = atomicAdd(&hist[b], 1);
                bn_rk[it][j] = (b << 16) | rk;
                pkv[it][j] = (ss[j] << 7) | (dd[j] - b * RW);
            }
        } else {
#pragma unroll
            for (int j = 0; j < 4; ++j) bn_rk[it][j] = -1;
        }
    }
    __syncthreads();
    int b4 = tid * 4;
    int h0 = hist[b4], h1 = hist[b4 + 1], h2 = hist[b4 + 2], h3 = hist[b4 + 3];
    int hs = h0 + h1 + h2 + h3;
    tsum[tid] = hs;
    __syncthreads();
    for (int d = 1; d < 256; d <<= 1) {
        int t = (tid >= d) ? tsum[tid - d] : 0;
        __syncthreads();
        tsum[tid] += t;
        __syncthreads();
    }
    int ex = tsum[tid] - hs;
    lofs[b4] = ex; lofs[b4 + 1] = ex + h0;
    lofs[b4 + 2] = ex + h0 + h1; lofs[b4 + 3] = ex + h0 + h1 + h2;
    if (tid == 255) lofs[NRB] = tsum[255];
    for (int b = tid; b < NRB; b += 256) {
        int cb = hist[b];
        gbase[b] = cb ? atomicAdd(&bcur[b], cb) : 0;
    }
    __syncthreads();
#pragma unroll
    for (int it = 0; it < 4; ++it)
#pragma unroll
        for (int j = 0; j < 4; ++j) {
            int br = bn_rk[it][j];
            if (br >= 0)
                pk[lofs[br >> 16] + (br & 0xffff)] = pkv[it][j];
        }
    __syncthreads();
    int total = lofs[NRB];
    for (int i = tid; i < total; i += 256) {
        int lo = 0, hi = NRB;
        while (hi - lo > 1) {
            int mid = (lo + hi) >> 1;
            if (lofs[mid] <= i) lo = mid; else hi = mid;
        }
        int pos = gbase[lo] + (i - lofs[lo]);
        if (pos < RCAP) bpk[lo * RCAP + pos] = pk[i];
    }
}

// ============== K2: per-range histogram ===================================
__global__ __launch_bounds__(256) void hist_nr_kernel(
        const int* __restrict__ bcur,
        const int* __restrict__ bpk,
        int* __restrict__ cnt) {
    __shared__ int lh[RW];
    int r = blockIdx.x, tid = threadIdx.x;
    if (tid < RW) lh[tid] = 0;
    __syncthreads();
    int nb = min(bcur[r], RCAP);
    const int* p = bpk + r * RCAP;
    for (int i = tid; i < nb; i += 256)
        atomicAdd(&lh[p[i] & 127], 1);
    __syncthreads();
    int n = r * RW + tid;
    if (tid < RW && n < N_NODES) cnt[n] = lh[tid];
}

__global__ void scan_block_kernel(const int* __restrict__ cnt,
                                  int* __restrict__ ofs,
                                  int* __restrict__ partial) {
    __shared__ int s[256];
    int tid = threadIdx.x;
    int i = blockIdx.x * 256 + tid;
    int v = (i < N_NODES) ? ((cnt[i] + 7) & ~7) : 0;
    s[tid] = v;
    __syncthreads();
    for (int d = 1; d < 256; d <<= 1) {
        int t = (tid >= d) ? s[tid - d] : 0;
        __syncthreads();
        s[tid] += t;
        __syncthreads();
    }
    if (i < N_NODES) ofs[i] = s[tid] - v;
    if (tid == 255) partial[blockIdx.x] = s[255];
}

__global__ void scan_partials_kernel(int* __restrict__ partial, int nb) {
    __shared__ int s[512];
    int tid = threadIdx.x;
    int v = (tid < nb) ? partial[tid] : 0;
    s[tid] = v;
    __syncthreads();
    for (int d = 1; d < 512; d <<= 1) {
        int t = (tid >= d) ? s[tid - d] : 0;
        __syncthreads();
        s[tid] += t;
        __syncthreads();
    }
    if (tid < nb) partial[tid] = s[tid] - v;
}

__global__ void scan_add_kernel(int* __restrict__ ofs,
                                const int* __restrict__ partial,
                                const int* __restrict__ cnt,
                                int* __restrict__ esrc) {
    int i = blockIdx.x * 256 + threadIdx.x;
    if (i < N_NODES) {
        int o = ofs[i] + partial[blockIdx.x];
        ofs[i] = o;
        int c = cnt[i], p = (c + 7) & ~7;
        for (int j = c; j < p; ++j) esrc[o + j] = SENTINEL;
        if (i == N_NODES - 1) ofs[N_NODES] = o + p;
    }
}

// ============== K5: place edges (LDS cursors, plain stores) ===============
__global__ __launch_bounds__(256) void place_nr_kernel(
        const int* __restrict__ bcur,
        const int* __restrict__ bpk,
        const int* __restrict__ ofs,
        int* __restrict__ esrc) {
    __shared__ int lof[RW];
    __shared__ int lcur[RW];
    int r = blockIdx.x, tid = threadIdx.x;
    int n = r * RW + tid;
    if (tid < RW) {
        lof[tid] = (n < N_NODES) ? ofs[n] : 0;
        lcur[tid] = 0;
    }
    __syncthreads();
    int nb = min(bcur[r], RCAP);
    const int* p = bpk + r * RCAP;
    for (int i = tid; i < nb; i += 256) {
        int v = p[i];
        int dl = v & 127;
        int rk = atomicAdd(&lcur[dl], 1);
        esrc[lof[dl] + rk] = (unsigned)v >> 7;
    }
}

// --- Fallback CSR (round-10 path, if ws too small) ------------------------
__global__ __launch_bounds__(256) void hist_kernel(const int* __restrict__ dst,
                                                   int* __restrict__ cnt) {
    int g = blockIdx.x & (NXCD - 1);
    int lo = g * DRANGE, hi = lo + DRANGE;
    int t = (blockIdx.x >> 3) * 256 + threadIdx.x;
    const int NCH = N_EDGES / 4;
    const int STRIDE = (GRID / NXCD) * 256;
    for (int c = t; c < NCH; c += STRIDE) {
        int4 d4 = ((const int4*)dst)[c];
        if (d4.x >= lo && d4.x < hi) atomicAdd(&cnt[d4.x], 1);
        if (d4.y >= lo && d4.y < hi) atomicAdd(&cnt[d4.y], 1);
        if (d4.z >= lo && d4.z < hi) atomicAdd(&cnt[d4.z], 1);
        if (d4.w >= lo && d4.w < hi) atomicAdd(&cnt[d4.w], 1);
    }
}

__global__ __launch_bounds__(256) void scatter_edges_kernel(
        const int* __restrict__ src,
        const int* __restrict__ dst,
        const int* __restrict__ ofs,
        int* __restrict__ cnt,
        int* __restrict__ esrc) {
    int g = blockIdx.x & (NXCD - 1);
    int lo = g * DRANGE, hi = lo + DRANGE;
    int t = (blockIdx.x >> 3) * 256 + threadIdx.x;
    const int NCH = N_EDGES / 4;
    const int STRIDE = (GRID / NXCD) * 256;
    for (int c = t; c < NCH; c += STRIDE) {
        int4 s4 = ((const int4*)src)[c];
        int4 d4 = ((const int4*)dst)[c];
        if (d4.x >= lo && d4.x < hi) esrc[ofs[d4.x] + atomicSub(&cnt[d4.x], 1) - 1] = s4.x;
        if (d4.y >= lo && d4.y < hi) esrc[ofs[d4.y] + atomicSub(&cnt[d4.y], 1) - 1] = s4.y;
        if (d4.z >= lo && d4.z < hi) esrc[ofs[d4.z] + atomicSub(&cnt[d4.z], 1) - 1] = s4.z;
        if (d4.w >= lo && d4.w < hi) esrc[ofs[d4.w] + atomicSub(&cnt[d4.w], 1) - 1] = s4.w;
    }
}

// ====== Prep: x->fp16 CHUNK-MAJOR, W->fp16, zero sentinel rows ============
// chunk-major: h[c][n][16ch], c = channel>>4.
__global__ void prep_kernel(const float* __restrict__ x,
                            const float* __restrict__ W0,
                            const float* __restrict__ W1,
                            const float* __restrict__ W2,
                            __half* __restrict__ x16,
                            __half* __restrict__ w16,
                            __half* __restrict__ bufA,
                            __half* __restrict__ bufB) {
    int b = blockIdx.x;
    if (b < NB_CVT) {
        int i = b * 256 + threadIdx.x;     // float4 index: node n, j = i%16
        int n = i >> 4, j = i & 15;        // channels 4j..4j+3, chunk j>>2
        float4 v = ((const float4*)x)[i];
        __half2 h01 = __floats2half2_rn(v.x, v.y);
        __half2 h23 = __floats2half2_rn(v.z, v.w);
        unsigned* hp = (unsigned*)x16 + (size_t)(j >> 2) * CHS_U + n * 8 + 2 * (j & 3);
        hp[0] = *(unsigned*)&h01;
        hp[1] = *(unsigned*)&h23;
    } else if (b < NB_CVT + 3) {
        int l = b - NB_CVT;
        const float* W = (l == 0) ? W0 : (l == 1) ? W1 : W2;
        for (int j = threadIdx.x; j < D * D; j += 256)
            w16[l * D * D + j] = __float2half(W[j]);
    } else {
        int tid = threadIdx.x;             // 96 lanes: 3 bufs x 4 chunks x 8 uints
        if (tid < 96) {
            __half* p = (tid < 32) ? x16 : (tid < 64) ? bufA : bufB;
            int t = tid & 31;
            ((unsigned*)p)[(size_t)(t >> 3) * CHS_U + (size_t)SENTINEL * 8 + (t & 7)] = 0u;
        }
    }
}

// ================= Gather (chunk-phased): S = h_self + sum h_nbr ==========
// Phase = chunk (blockIdx/NBC): all CUs gather one 3.2MB chunk at a time ->
// each XCD's L2 holds a replica -> gathers are L2 HITS, not L3 misses.
// 8 lanes per node (4B=2ch each); idx: 1 coalesced load + width-8 shfls.
__global__ __launch_bounds__(256) void gather_kernel(
        const __half* __restrict__ h_in,
        const int* __restrict__ ofs,
        const int* __restrict__ esrc,
        __half* __restrict__ s_out) {
    int c = blockIdx.x / NBC;              // chunk phase 0..3
    int nb = blockIdx.x - c * NBC;
    int tid = threadIdx.x;
    int g = tid >> 3;                      // 32 node-groups per block
    int l = tid & 7;
    int n = nb * 32 + g;
    const unsigned* hp = (const unsigned*)h_in + (size_t)c * CHS_U;

    unsigned selfv = hp[n * 8 + l];
    float2 acc = __half22float2(*(__half2*)&selfv);

    int k = ofs[n], end = ofs[n + 1];
    for (; k < end; k += 8) {
        int idx = esrc[k + l];             // 8 lanes: one 32B transaction
        int s0 = __shfl(idx, 0, 8), s1 = __shfl(idx, 1, 8);
        int s2 = __shfl(idx, 2, 8), s3 = __shfl(idx, 3, 8);
        int s4 = __shfl(idx, 4, 8), s5 = __shfl(idx, 5, 8);
        int s6 = __shfl(idx, 6, 8), s7 = __shfl(idx, 7, 8);
        unsigned r0 = hp[s0 * 8 + l];
        unsigned r1 = hp[s1 * 8 + l];
        unsigned r2 = hp[s2 * 8 + l];
        unsigned r3 = hp[s3 * 8 + l];
        unsigned r4 = hp[s4 * 8 + l];
        unsigned r5 = hp[s5 * 8 + l];
        unsigned r6 = hp[s6 * 8 + l];
        unsigned r7 = hp[s7 * 8 + l];
#define ACC(R) { float2 q = __half22float2(*(__half2*)&R); acc.x += q.x; acc.y += q.y; }
        ACC(r0) ACC(r1) ACC(r2) ACC(r3) ACC(r4) ACC(r5) ACC(r6) ACC(r7)
#undef ACC
    }
    __half2 hv = __floats2half2_rn(acc.x, acc.y);
    ((unsigned*)s_out)[(size_t)c * CHS_U + n * 8 + l] = *(unsigned*)&hv;
}

// ================= MLP: h' = relu(S @ W) via MFMA (chunk-major I/O) =======
// A fragment (16B) stays contiguous: halfs [kg*8, kg*8+8) = chunk kg>>1,
// offset (kg&1)*8; +32 halfs = chunk +2. C store re-addressed to chunks.
__global__ __launch_bounds__(256) void mlp_kernel(
        const __half* __restrict__ S,
        const __half* __restrict__ W16,
        __half* __restrict__ h_out) {
    int w = threadIdx.x >> 6, lane = threadIdx.x & 63;
    int m = lane & 15;
    int kg = lane >> 4;
    const _Float16* Wp = (const _Float16*)W16;
    f16x8 bf[4][2];
#pragma unroll
    for (int ct = 0; ct < 4; ++ct)
#pragma unroll
        for (int kt = 0; kt < 2; ++kt)
#pragma unroll
            for (int j = 0; j < 8; ++j)
                bf[ct][kt][j] = Wp[(kt * 32 + kg * 8 + j) * D + ct * 16 + m];

    int t = blockIdx.x * 4 + w;
    if (t >= N_NODES / 16) return;
    const _Float16* Sp = (const _Float16*)S;
    int row = t * 16 + m;
    f16x8 a0 = *(const f16x8*)(Sp + (size_t)(kg >> 1) * CHS_H + row * 16 + (kg & 1) * 8);
    f16x8 a1 = *(const f16x8*)(Sp + (size_t)((kg >> 1) + 2) * CHS_H + row * 16 + (kg & 1) * 8);
    f32x4 c[4];
#pragma unroll
    for (int ct = 0; ct < 4; ++ct) {
        f32x4 z = {0.f, 0.f, 0.f, 0.f};
        z = __builtin_amdgcn_mfma_f32_16x16x32_f16(a0, bf[ct][0], z, 0, 0, 0);
        z = __builtin_amdgcn_mfma_f32_16x16x32_f16(a1, bf[ct][1], z, 0, 0, 0);
        c[ct] = z;
    }
#pragma unroll
    for (int ct = 0; ct < 4; ++ct)
#pragma unroll
        for (int r = 0; r < 4; ++r)
            ((_Float16*)h_out)[(size_t)ct * CHS_H + (t * 16 + kg * 4 + r) * 16 + m] =
                (_Float16)fmaxf(c[ct][r], 0.f);
}

// ============ Final: L2-normalize + 64->16 linear (chunk-major in) ========
__global__ __launch_bounds__(256) void final_kernel(
        const __half* __restrict__ h,
        const float* __restrict__ W_out,
        const float* __restrict__ b_out,
        float* __restrict__ out,    // [N,16] row-major
        float* __restrict__ feat) { // [N,64] row-major
    __shared__ float Wo[D][N_CLASSES];
    __shared__ float fs[4][2][D];
    int tid = threadIdx.x;
    for (int k = tid; k < D * N_CLASSES; k += 256)
        Wo[k >> 4][k & 15] = W_out[k];
    __syncthreads();
    int w = tid >> 6;
    int lane = tid & 63;
    int hh = lane >> 5;
    int c2 = lane & 31;                 // half2 slot; true channel = (c2>>3)*16+(c2&7)*2
    int ch = (c2 >> 3) * 16 + (c2 & 7) * 2;
    const __half2* hp = (const __half2*)h;
    float bias = b_out[lane & 15];

    for (int g = blockIdx.x; g < NG8; g += GRID) {
        int n = g * 8 + w * 2 + hh;
        float2 v = __half22float2(hp[(size_t)(c2 >> 3) * CHS_H2 + n * 8 + (c2 & 7)]);
        float ss = v.x * v.x + v.y * v.y;
#pragma unroll
        for (int off = 16; off; off >>= 1)   // within half-wave
            ss += __shfl_xor(ss, off);
        float rinv = 1.f / fmaxf(sqrtf(ss), 1e-12f);
        float f0 = v.x * rinv, f1 = v.y * rinv;
        *(float2*)&feat[(size_t)n * D + ch] = make_float2(f0, f1);
        fs[w][hh][ch + 0] = f0;
        fs[w][hh][ch + 1] = f1;
        if (c2 < N_CLASSES) {
            float acc = bias;
#pragma unroll
            for (int i = 0; i < D; ++i)
                acc = fmaf(fs[w][hh][i], Wo[i][c2], acc);
            out[(size_t)n * N_CLASSES + c2] = acc;
        }
    }
}

// ==========================================================================
extern "C" void kernel_launch(void* const* d_in, const int* in_sizes, int n_in,
                              void* d_out, int out_size, void* d_ws, size_t ws_size,
                              hipStream_t stream) {
    const float* x     = (const float*)d_in[0];
    const int*   src   = (const int*)d_in[1];
    const int*   dst   = (const int*)d_in[2];
    const float* W0    = (const float*)d_in[3];
    const float* W1    = (const float*)d_in[4];
    const float* W2    = (const float*)d_in[5];
    const float* W_out = (const float*)d_in[6];
    const float* b_out = (const float*)d_in[7];

    float* out  = (float*)d_out;
    float* feat = (float*)d_out + (size_t)N_NODES * N_CLASSES;

    const int NB_NODE = (N_NODES + 255) / 256;       // 391
    const int NB_MLP  = (N_NODES / 16 + 3) / 4;      // 1563

    size_t off = 0;
    auto alloc = [&](size_t bytes) { size_t o = off; off = (off + bytes + 255) & ~(size_t)255; return o; };
    size_t o_cnt     = alloc((size_t)N_NODES * 4);
    size_t o_partial = alloc(512 * 4);
    size_t o_ofs     = alloc(((size_t)N_NODES + 1) * 4);
    size_t o_esrc    = alloc((size_t)ESRC_CAP * 4);
    size_t o_w16     = alloc((size_t)3 * D * D * 2);
    size_t o_X       = alloc((size_t)NCHK * CHS_H * 2);
    size_t o_A       = alloc((size_t)NCHK * CHS_H * 2);
    size_t o_B       = alloc((size_t)NCHK * CHS_H * 2);
    size_t o_bcur    = alloc((size_t)NRB * 4);
    size_t o_bpk     = alloc((size_t)NRB * RCAP * 4);
    size_t need_bkt  = off;

    char* w8 = (char*)d_ws;
    int*    cnt     = (int*)(w8 + o_cnt);
    int*    partial = (int*)(w8 + o_partial);
    int*    ofs     = (int*)(w8 + o_ofs);
    int*    esrc    = (int*)(w8 + o_esrc);
    __half* w16     = (__half*)(w8 + o_w16);
    __half* X       = (__half*)(w8 + o_X);
    __half* A       = (__half*)(w8 + o_A);
    __half* B       = (__half*)(w8 + o_B);

    if (ws_size >= need_bkt) {
        int* bcur = (int*)(w8 + o_bcur);
        int* bpk  = (int*)(w8 + o_bpk);
        hipMemsetAsync(bcur, 0, (size_t)NRB * 4, stream);
        bucket_nr_kernel<<<K1B, 256, 0, stream>>>(src, dst, bcur, bpk);
        hist_nr_kernel<<<NRB, 256, 0, stream>>>(bcur, bpk, cnt);
        scan_block_kernel<<<NB_NODE, 256, 0, stream>>>(cnt, ofs, partial);
        scan_partials_kernel<<<1, 512, 0, stream>>>(partial, NB_NODE);
        scan_add_kernel<<<NB_NODE, 256, 0, stream>>>(ofs, partial, cnt, esrc);
        place_nr_kernel<<<NRB, 256, 0, stream>>>(bcur, bpk, ofs, esrc);
    } else {
        hipMemsetAsync(cnt, 0, (size_t)N_NODES * 4, stream);
        hist_kernel<<<GRID, 256, 0, stream>>>(dst, cnt);
        scan_block_kernel<<<NB_NODE, 256, 0, stream>>>(cnt, ofs, partial);
        scan_partials_kernel<<<1, 512, 0, stream>>>(partial, NB_NODE);
        scan_add_kernel<<<NB_NODE, 256, 0, stream>>>(ofs, partial, cnt, esrc);
        scatter_edges_kernel<<<GRID, 256, 0, stream>>>(src, dst, ofs, cnt, esrc);
    }

    prep_kernel<<<NB_CVT + 4, 256, 0, stream>>>(x, W0, W1, W2, X, w16, A, B);

    gather_kernel<<<NCHK * NBC, 256, 0, stream>>>(X, ofs, esrc, A);
    mlp_kernel<<<NB_MLP, 256, 0, stream>>>(A, w16 + 0 * D * D, B);
    gather_kernel<<<NCHK * NBC, 256, 0, stream>>>(B, ofs, esrc, X);
    mlp_kernel<<<NB_MLP, 256, 0, stream>>>(X, w16 + 1 * D * D, A);
    gather_kernel<<<NCHK * NBC, 256, 0, stream>>>(A, ofs, esrc, B);
    mlp_kernel<<<NB_MLP, 256, 0, stream>>>(B, w16 + 2 * D * D, X);

    final_kernel<<<GRID, 256, 0, stream>>>(X, W_out, b_out, out, feat);
}

// Round 15
// 209.332 us; speedup vs baseline: 1.0628x; 1.0628x over previous
//
#include <hip/hip_runtime.h>
#include <hip/hip_fp16.h>

#define N_NODES 100000
#define N_EDGES 1200000
#define D 64
#define N_CLASSES 16
#define NG8  (N_NODES / 8)
#define GRID 2048
#define NXCD 8
#define DRANGE ((N_NODES + NXCD - 1) / NXCD)
#define ESRC_CAP 1900032           // >= E + 7N (pad-8)
#define SENTINEL N_NODES           // index of the all-zero h row
#define NB_CVT 6250
// node-range counting sort
#define NRB 1024
#define RW 98
#define RCAP 2048
#define K1CH 1024
#define K1B ((N_EDGES / 4 + K1CH - 1) / K1CH)   // 293
#define DBINS 16                   // degree buckets: ceil(deg/8), clamped

typedef _Float16 f16x8 __attribute__((ext_vector_type(8)));
typedef float    f32x4 __attribute__((ext_vector_type(4)));

// ============== K1: bin edges into 1024 node-range buckets ================
__global__ __launch_bounds__(256) void bucket_nr_kernel(
        const int* __restrict__ src,
        const int* __restrict__ dst,
        int* __restrict__ bcur,          // [NRB]
        int* __restrict__ bpk) {         // [NRB][RCAP]
    __shared__ int hist[NRB];
    __shared__ int lofs[NRB + 1];
    __shared__ int gbase[NRB];
    __shared__ int tsum[256];
    __shared__ int pk[K1CH * 4];         // 16KB
    int tid = threadIdx.x;
    for (int i = tid; i < NRB; i += 256) hist[i] = 0;
    __syncthreads();

    int c0 = blockIdx.x * K1CH;
    int bn_rk[4][4], pkv[4][4];
#pragma unroll
    for (int it = 0; it < 4; ++it) {
        int c = c0 + it * 256 + tid;
        if (c < N_EDGES / 4) {
            int4 s4 = ((const int4*)src)[c];
            int4 d4 = ((const int4*)dst)[c];
            int ss[4] = {s4.x, s4.y, s4.z, s4.w};
            int dd[4] = {d4.x, d4.y, d4.z, d4.w};
#pragma unroll
            for (int j = 0; j < 4; ++j) {
                int b = dd[j] / RW;
                int rk = atomicAdd(&hist[b], 1);
                bn_rk[it][j] = (b << 16) | rk;
                pkv[it][j] = (ss[j] << 7) | (dd[j] - b * RW);
            }
        } else {
#pragma unroll
            for (int j = 0; j < 4; ++j) bn_rk[it][j] = -1;
        }
    }
    __syncthreads();
    int b4 = tid * 4;
    int h0 = hist[b4], h1 = hist[b4 + 1], h2 = hist[b4 + 2], h3 = hist[b4 + 3];
    int hs = h0 + h1 + h2 + h3;
    tsum[tid] = hs;
    __syncthreads();
    for (int d = 1; d < 256; d <<= 1) {
        int t = (tid >= d) ? tsum[tid - d] : 0;
        __syncthreads();
        tsum[tid] += t;
        __syncthreads();
    }
    int ex = tsum[tid] - hs;
    lofs[b4] = ex; lofs[b4 + 1] = ex + h0;
    lofs[b4 + 2] = ex + h0 + h1; lofs[b4 + 3] = ex + h0 + h1 + h2;
    if (tid == 255) lofs[NRB] = tsum[255];
    for (int b = tid; b < NRB; b += 256) {
        int cb = hist[b];
        gbase[b] = cb ? atomicAdd(&bcur[b], cb) : 0;
    }
    __syncthreads();
#pragma unroll
    for (int it = 0; it < 4; ++it)
#pragma unroll
        for (int j = 0; j < 4; ++j) {
            int br = bn_rk[it][j];
            if (br >= 0)
                pk[lofs[br >> 16] + (br & 0xffff)] = pkv[it][j];
        }
    __syncthreads();
    int total = lofs[NRB];
    for (int i = tid; i < total; i += 256) {
        int lo = 0, hi = NRB;
        while (hi - lo > 1) {
            int mid = (lo + hi) >> 1;
            if (lofs[mid] <= i) lo = mid; else hi = mid;
        }
        int pos = gbase[lo] + (i - lofs[lo]);
        if (pos < RCAP) bpk[lo * RCAP + pos] = pk[i];
    }
}

// ============== K2: per-range histogram ===================================
__global__ __launch_bounds__(256) void hist_nr_kernel(
        const int* __restrict__ bcur,
        const int* __restrict__ bpk,
        int* __restrict__ cnt) {
    __shared__ int lh[RW];
    int r = blockIdx.x, tid = threadIdx.x;
    if (tid < RW) lh[tid] = 0;
    __syncthreads();
    int nb = min(bcur[r], RCAP);
    const int* p = bpk + r * RCAP;
    for (int i = tid; i < nb; i += 256)
        atomicAdd(&lh[p[i] & 127], 1);
    __syncthreads();
    int n = r * RW + tid;
    if (tid < RW && n < N_NODES) cnt[n] = lh[tid];
}

__global__ void scan_block_kernel(const int* __restrict__ cnt,
                                  int* __restrict__ ofs,
                                  int* __restrict__ partial) {
    __shared__ int s[256];
    int tid = threadIdx.x;
    int i = blockIdx.x * 256 + tid;
    int v = (i < N_NODES) ? ((cnt[i] + 7) & ~7) : 0;
    s[tid] = v;
    __syncthreads();
    for (int d = 1; d < 256; d <<= 1) {
        int t = (tid >= d) ? s[tid - d] : 0;
        __syncthreads();
        s[tid] += t;
        __syncthreads();
    }
    if (i < N_NODES) ofs[i] = s[tid] - v;
    if (tid == 255) partial[blockIdx.x] = s[255];
}

__global__ void scan_partials_kernel(int* __restrict__ partial, int nb) {
    __shared__ int s[512];
    int tid = threadIdx.x;
    int v = (tid < nb) ? partial[tid] : 0;
    s[tid] = v;
    __syncthreads();
    for (int d = 1; d < 512; d <<= 1) {
        int t = (tid >= d) ? s[tid - d] : 0;
        __syncthreads();
        s[tid] += t;
        __syncthreads();
    }
    if (tid < nb) partial[tid] = s[tid] - v;
}

__global__ void scan_add_kernel(int* __restrict__ ofs,
                                const int* __restrict__ partial,
                                const int* __restrict__ cnt,
                                int* __restrict__ esrc) {
    int i = blockIdx.x * 256 + threadIdx.x;
    if (i < N_NODES) {
        int o = ofs[i] + partial[blockIdx.x];
        ofs[i] = o;
        int c = cnt[i], p = (c + 7) & ~7;
        for (int j = c; j < p; ++j) esrc[o + j] = SENTINEL;
        if (i == N_NODES - 1) ofs[N_NODES] = o + p;
    }
}

// ============== K5: place edges (LDS cursors, plain stores) ===============
__global__ __launch_bounds__(256) void place_nr_kernel(
        const int* __restrict__ bcur,
        const int* __restrict__ bpk,
        const int* __restrict__ ofs,
        int* __restrict__ esrc) {
    __shared__ int lof[RW];
    __shared__ int lcur[RW];
    int r = blockIdx.x, tid = threadIdx.x;
    int n = r * RW + tid;
    if (tid < RW) {
        lof[tid] = (n < N_NODES) ? ofs[n] : 0;
        lcur[tid] = 0;
    }
    __syncthreads();
    int nb = min(bcur[r], RCAP);
    const int* p = bpk + r * RCAP;
    for (int i = tid; i < nb; i += 256) {
        int v = p[i];
        int dl = v & 127;
        int rk = atomicAdd(&lcur[dl], 1);
        esrc[lof[dl] + rk] = (unsigned)v >> 7;
    }
}

// ====== Degree-sort permutation: bucket = ceil(deg/8), counting sort ======
__global__ void hist_deg_kernel(const int* __restrict__ cnt, int* __restrict__ gd) {
    __shared__ int lh[DBINS];
    int tid = threadIdx.x;
    if (tid < DBINS) lh[tid] = 0;
    __syncthreads();
    int i = blockIdx.x * 256 + tid;
    if (i < N_NODES) atomicAdd(&lh[min((cnt[i] + 7) >> 3, DBINS - 1)], 1);
    __syncthreads();
    if (tid < DBINS && lh[tid]) atomicAdd(&gd[tid], lh[tid]);
}

__global__ void scan_deg_kernel(int* __restrict__ gd) {
    if (threadIdx.x == 0) {
        int acc = 0;
        for (int b = 0; b < DBINS; ++b) { int v = gd[b]; gd[DBINS + b] = acc; acc += v; }
    }
}

__global__ void perm_kernel(const int* __restrict__ cnt,
                            int* __restrict__ gd,       // [16 hist][16 cursors]
                            int* __restrict__ perm) {
    __shared__ int lh[DBINS], lbase[DBINS];
    int tid = threadIdx.x;
    if (tid < DBINS) lh[tid] = 0;
    __syncthreads();
    int i = blockIdx.x * 256 + tid;
    int b = -1;
    if (i < N_NODES) {
        b = min((cnt[i] + 7) >> 3, DBINS - 1);
        atomicAdd(&lh[b], 1);
    }
    __syncthreads();
    if (tid < DBINS) {
        lbase[tid] = lh[tid] ? atomicAdd(&gd[DBINS + tid], lh[tid]) : 0;
        lh[tid] = 0;
    }
    __syncthreads();
    if (i < N_NODES) {
        int r = atomicAdd(&lh[b], 1);
        perm[lbase[b] + r] = i;
    }
}

// --- Fallback CSR (round-10 path, if ws too small) ------------------------
__global__ __launch_bounds__(256) void hist_kernel(const int* __restrict__ dst,
                                                   int* __restrict__ cnt) {
    int g = blockIdx.x & (NXCD - 1);
    int lo = g * DRANGE, hi = lo + DRANGE;
    int t = (blockIdx.x >> 3) * 256 + threadIdx.x;
    const int NCH = N_EDGES / 4;
    const int STRIDE = (GRID / NXCD) * 256;
    for (int c = t; c < NCH; c += STRIDE) {
        int4 d4 = ((const int4*)dst)[c];
        if (d4.x >= lo && d4.x < hi) atomicAdd(&cnt[d4.x], 1);
        if (d4.y >= lo && d4.y < hi) atomicAdd(&cnt[d4.y], 1);
        if (d4.z >= lo && d4.z < hi) atomicAdd(&cnt[d4.z], 1);
        if (d4.w >= lo && d4.w < hi) atomicAdd(&cnt[d4.w], 1);
    }
}

__global__ __launch_bounds__(256) void scatter_edges_kernel(
        const int* __restrict__ src,
        const int* __restrict__ dst,
        const int* __restrict__ ofs,
        int* __restrict__ cnt,
        int* __restrict__ esrc) {
    int g = blockIdx.x & (NXCD - 1);
    int lo = g * DRANGE, hi = lo + DRANGE;
    int t = (blockIdx.x >> 3) * 256 + threadIdx.x;
    const int NCH = N_EDGES / 4;
    const int STRIDE = (GRID / NXCD) * 256;
    for (int c = t; c < NCH; c += STRIDE) {
        int4 s4 = ((const int4*)src)[c];
        int4 d4 = ((const int4*)dst)[c];
        if (d4.x >= lo && d4.x < hi) esrc[ofs[d4.x] + atomicSub(&cnt[d4.x], 1) - 1] = s4.x;
        if (d4.y >= lo && d4.y < hi) esrc[ofs[d4.y] + atomicSub(&cnt[d4.y], 1) - 1] = s4.y;
        if (d4.z >= lo && d4.z < hi) esrc[ofs[d4.z] + atomicSub(&cnt[d4.z], 1) - 1] = s4.z;
        if (d4.w >= lo && d4.w < hi) esrc[ofs[d4.w] + atomicSub(&cnt[d4.w], 1) - 1] = s4.w;
    }
}

// Identity permutation (fallback path)
__global__ void iota_kernel(int* __restrict__ perm) {
    int i = blockIdx.x * 256 + threadIdx.x;
    if (i < N_NODES) perm[i] = i;
}

// ====== Prep: x->fp16, W0..W2->fp16, zero sentinel rows (one kernel) ======
__global__ void prep_kernel(const float* __restrict__ x,
                            const float* __restrict__ W0,
                            const float* __restrict__ W1,
                            const float* __restrict__ W2,
                            __half* __restrict__ x16,
                            __half* __restrict__ w16,
                            __half* __restrict__ bufA,
                            __half* __restrict__ bufB) {
    int b = blockIdx.x;
    if (b < NB_CVT) {
        int i = b * 256 + threadIdx.x;
        float4 v = ((const float4*)x)[i];
        ((__half2*)x16)[2 * i + 0] = __floats2half2_rn(v.x, v.y);
        ((__half2*)x16)[2 * i + 1] = __floats2half2_rn(v.z, v.w);
    } else if (b < NB_CVT + 3) {
        int l = b - NB_CVT;
        const float* W = (l == 0) ? W0 : (l == 1) ? W1 : W2;
        for (int j = threadIdx.x; j < D * D; j += 256)
            w16[l * D * D + j] = __float2half(W[j]);
    } else {
        int tid = threadIdx.x;
        if (tid < 96) {
            __half* p = (tid < 32) ? x16 : (tid < 64) ? bufA : bufB;
            ((unsigned int*)(p + SENTINEL * D))[tid & 31] = 0u;
        }
    }
}

// ================= Gather: S[n] = h[n] + sum_neighbors h ==================
// Degree-sorted: group's node comes from perm[] so all 4 quarter-groups in a
// wave share the same ceil(deg/8) -> no masked-lane straggler waste.
__global__ __launch_bounds__(256) void gather_kernel(
        const __half* __restrict__ h_in,
        const int* __restrict__ ofs,
        const int* __restrict__ esrc,
        const int* __restrict__ perm,
        __half* __restrict__ s_out) {
    int w = threadIdx.x >> 6, lane = threadIdx.x & 63;
    int q = lane >> 4;
    int c4 = lane & 15;
    int n = perm[blockIdx.x * 16 + w * 4 + q];   // broadcast within group
    const uint2* hp = (const uint2*)h_in;

    uint2 self = hp[n * 16 + c4];
    float2 sl = __half22float2(*(const __half2*)&self.x);
    float2 sh = __half22float2(*(const __half2*)&self.y);
    float a0 = sl.x, a1 = sl.y, a2 = sh.x, a3 = sh.y;

    int k = ofs[n], end = ofs[n + 1];
    for (; k < end; k += 8) {
        int4 i0 = *(const int4*)(esrc + k);
        int4 i1 = *(const int4*)(esrc + k + 4);
        uint2 r0 = hp[i0.x * 16 + c4];
        uint2 r1 = hp[i0.y * 16 + c4];
        uint2 r2 = hp[i0.z * 16 + c4];
        uint2 r3 = hp[i0.w * 16 + c4];
        uint2 r4 = hp[i1.x * 16 + c4];
        uint2 r5 = hp[i1.y * 16 + c4];
        uint2 r6 = hp[i1.z * 16 + c4];
        uint2 r7 = hp[i1.w * 16 + c4];
#define ACC(R) { float2 lo = __half22float2(*(const __half2*)&R.x); \
                 float2 hi = __half22float2(*(const __half2*)&R.y); \
                 a0 += lo.x; a1 += lo.y; a2 += hi.x; a3 += hi.y; }
        ACC(r0) ACC(r1) ACC(r2) ACC(r3) ACC(r4) ACC(r5) ACC(r6) ACC(r7)
#undef ACC
    }
    uint2 ov;
    *(__half2*)&ov.x = __floats2half2_rn(a0, a1);
    *(__half2*)&ov.y = __floats2half2_rn(a2, a3);
    ((uint2*)s_out)[n * 16 + c4] = ov;   // full 128B row per group
}

// ================= MLP: h' = relu(S @ W) via MFMA =========================
__global__ __launch_bounds__(256) void mlp_kernel(
        const __half* __restrict__ S,
        const __half* __restrict__ W16,
        __half* __restrict__ h_out) {
    int w = threadIdx.x >> 6, lane = threadIdx.x & 63;
    int m = lane & 15;
    int kg = lane >> 4;
    const _Float16* Wp = (const _Float16*)W16;
    f16x8 bf[4][2];
#pragma unroll
    for (int ct = 0; ct < 4; ++ct)
#pragma unroll
        for (int kt = 0; kt < 2; ++kt)
#pragma unroll
            for (int j = 0; j < 8; ++j)
                bf[ct][kt][j] = Wp[(kt * 32 + kg * 8 + j) * D + ct * 16 + m];

    int t = blockIdx.x * 4 + w;
    if (t >= N_NODES / 16) return;
    const _Float16* Sp = (const _Float16*)S;
    int row = t * 16 + m;
    f16x8 a0 = *(const f16x8*)(Sp + row * D + kg * 8);
    f16x8 a1 = *(const f16x8*)(Sp + row * D + 32 + kg * 8);
    f32x4 c[4];
#pragma unroll
    for (int ct = 0; ct < 4; ++ct) {
        f32x4 z = {0.f, 0.f, 0.f, 0.f};
        z = __builtin_amdgcn_mfma_f32_16x16x32_f16(a0, bf[ct][0], z, 0, 0, 0);
        z = __builtin_amdgcn_mfma_f32_16x16x32_f16(a1, bf[ct][1], z, 0, 0, 0);
        c[ct] = z;
    }
#pragma unroll
    for (int ct = 0; ct < 4; ++ct)
#pragma unroll
        for (int r = 0; r < 4; ++r)
            h_out[(t * 16 + kg * 4 + r) * D + ct * 16 + m] =
                __float2half(fmaxf(c[ct][r], 0.f));
}

// ============ Final: L2-normalize + 64->16 linear (fp16 in) ===============
__global__ __launch_bounds__(256) void final_kernel(
        const __half* __restrict__ h,
        const float* __restrict__ W_out,
        const float* __restrict__ b_out,
        float* __restrict__ out,
        float* __restrict__ feat) {
    __shared__ float Wo[D][N_CLASSES];
    __shared__ float fs[4][2][D];
    int tid = threadIdx.x;
    for (int k = tid; k < D * N_CLASSES; k += 256)
        Wo[k >> 4][k & 15] = W_out[k];
    __syncthreads();
    int w = tid >> 6;
    int lane = tid & 63;
    int hh = lane >> 5;
    int c2 = lane & 31;
    const __half2* hp = (const __half2*)h;
    float bias = b_out[lane & 15];

    for (int g = blockIdx.x; g < NG8; g += GRID) {
        int n = g * 8 + w * 2 + hh;
        float2 v = __half22float2(hp[n * 32 + c2]);
        float ss = v.x * v.x + v.y * v.y;
#pragma unroll
        for (int off = 16; off; off >>= 1)
            ss += __shfl_xor(ss, off);
        float rinv = 1.f / fmaxf(sqrtf(ss), 1e-12f);
        float f0 = v.x * rinv, f1 = v.y * rinv;
        ((float2*)feat)[n * 32 + c2] = make_float2(f0, f1);
        fs[w][hh][2 * c2 + 0] = f0;
        fs[w][hh][2 * c2 + 1] = f1;
        if (c2 < N_CLASSES) {
            float acc = bias;
#pragma unroll
            for (int i = 0; i < D; ++i)
                acc = fmaf(fs[w][hh][i], Wo[i][c2], acc);
            out[n * N_CLASSES + c2] = acc;
        }
    }
}

// ==========================================================================
extern "C" void kernel_launch(void* const* d_in, const int* in_sizes, int n_in,
                              void* d_out, int out_size, void* d_ws, size_t ws_size,
                              hipStream_t stream) {
    const float* x     = (const float*)d_in[0];
    const int*   src   = (const int*)d_in[1];
    const int*   dst   = (const int*)d_in[2];
    const float* W0    = (const float*)d_in[3];
    const float* W1    = (const float*)d_in[4];
    const float* W2    = (const float*)d_in[5];
    const float* W_out = (const float*)d_in[6];
    const float* b_out = (const float*)d_in[7];

    float* out  = (float*)d_out;
    float* feat = (float*)d_out + (size_t)N_NODES * N_CLASSES;

    const int NB_NODE = (N_NODES + 255) / 256;       // 391
    const int NB_MLP  = (N_NODES / 16 + 3) / 4;      // 1563

    size_t off = 0;
    auto alloc = [&](size_t bytes) { size_t o = off; off = (off + bytes + 255) & ~(size_t)255; return o; };
    size_t o_cnt     = alloc((size_t)N_NODES * 4);
    size_t o_partial = alloc(512 * 4);
    size_t o_ofs     = alloc(((size_t)N_NODES + 1) * 4);
    size_t o_esrc    = alloc((size_t)ESRC_CAP * 4);
    size_t o_w16     = alloc((size_t)3 * D * D * 2);
    size_t o_X       = alloc((size_t)(N_NODES + 1) * D * 2);
    size_t o_A       = alloc((size_t)(N_NODES + 1) * D * 2);
    size_t o_B       = alloc((size_t)(N_NODES + 1) * D * 2);
    size_t o_perm    = alloc((size_t)N_NODES * 4);
    size_t o_gd      = alloc((size_t)2 * DBINS * 4);
    size_t o_bcur    = alloc((size_t)NRB * 4);
    size_t o_bpk     = alloc((size_t)NRB * RCAP * 4);
    size_t need_bkt  = off;

    char* w8 = (char*)d_ws;
    int*    cnt     = (int*)(w8 + o_cnt);
    int*    partial = (int*)(w8 + o_partial);
    int*    ofs     = (int*)(w8 + o_ofs);
    int*    esrc    = (int*)(w8 + o_esrc);
    __half* w16     = (__half*)(w8 + o_w16);
    __half* X       = (__half*)(w8 + o_X);
    __half* A       = (__half*)(w8 + o_A);
    __half* B       = (__half*)(w8 + o_B);
    int*    perm    = (int*)(w8 + o_perm);
    int*    gd      = (int*)(w8 + o_gd);

    if (ws_size >= need_bkt) {
        int* bcur = (int*)(w8 + o_bcur);
        int* bpk  = (int*)(w8 + o_bpk);
        hipMemsetAsync(bcur, 0, (size_t)NRB * 4, stream);
        hipMemsetAsync(gd, 0, (size_t)2 * DBINS * 4, stream);
        bucket_nr_kernel<<<K1B, 256, 0, stream>>>(src, dst, bcur, bpk);
        hist_nr_kernel<<<NRB, 256, 0, stream>>>(bcur, bpk, cnt);
        scan_block_kernel<<<NB_NODE, 256, 0, stream>>>(cnt, ofs, partial);
        scan_partials_kernel<<<1, 512, 0, stream>>>(partial, NB_NODE);
        scan_add_kernel<<<NB_NODE, 256, 0, stream>>>(ofs, partial, cnt, esrc);
        place_nr_kernel<<<NRB, 256, 0, stream>>>(bcur, bpk, ofs, esrc);
        // degree-sort permutation (uses cnt = true degrees)
        hist_deg_kernel<<<NB_NODE, 256, 0, stream>>>(cnt, gd);
        scan_deg_kernel<<<1, 64, 0, stream>>>(gd);
        perm_kernel<<<NB_NODE, 256, 0, stream>>>(cnt, gd, perm);
    } else {
        hipMemsetAsync(cnt, 0, (size_t)N_NODES * 4, stream);
        hist_kernel<<<GRID, 256, 0, stream>>>(dst, cnt);
        scan_block_kernel<<<NB_NODE, 256, 0, stream>>>(cnt, ofs, partial);
        scan_partials_kernel<<<1, 512, 0, stream>>>(partial, NB_NODE);
        scan_add_kernel<<<NB_NODE, 256, 0, stream>>>(ofs, partial, cnt, esrc);
        scatter_edges_kernel<<<GRID, 256, 0, stream>>>(src, dst, ofs, cnt, esrc);
        iota_kernel<<<NB_NODE, 256, 0, stream>>>(perm);
    }

    prep_kernel<<<NB_CVT + 4, 256, 0, stream>>>(x, W0, W1, W2, X, w16, A, B);

    gather_kernel<<<N_NODES / 16, 256, 0, stream>>>(X, ofs, esrc, perm, A);
    mlp_kernel<<<NB_MLP, 256, 0, stream>>>(A, w16 + 0 * D * D, B);
    gather_kernel<<<N_NODES / 16, 256, 0, stream>>>(B, ofs, esrc, perm, X);
    mlp_kernel<<<NB_MLP, 256, 0, stream>>>(X, w16 + 1 * D * D, A);
    gather_kernel<<<N_NODES / 16, 256, 0, stream>>>(A, ofs, esrc, perm, B);
    mlp_kernel<<<NB_MLP, 256, 0, stream>>>(B, w16 + 2 * D * D, X);

    final_kernel<<<GRID, 256, 0, stream>>>(X, W_out, b_out, out, feat);
}

// Round 16
// 194.663 us; speedup vs baseline: 1.1429x; 1.0754x over previous
//
#include <hip/hip_runtime.h>
#include <hip/hip_fp16.h>

#define N_NODES 100000
#define N_EDGES 1200000
#define D 64
#define N_CLASSES 16
#define NG8  (N_NODES / 8)
#define GRID 2048
#define NXCD 8
#define DRANGE ((N_NODES + NXCD - 1) / NXCD)
#define ESRC_CAP 1900032           // >= E + 7N (pad-8)
#define SENTINEL N_NODES           // index of the all-zero h row
#define NB_CVT 6250
// node-range counting sort
#define NRB 1024
#define RW 98
#define RCAP 2048
#define K1CH 512                   // int4 chunks per K1 block (2048 edges)
#define K1IT (K1CH / 256)          // 2
#define K1B ((N_EDGES / 4 + K1CH - 1) / K1CH)   // 586

typedef _Float16 f16x8 __attribute__((ext_vector_type(8)));
typedef float    f32x4 __attribute__((ext_vector_type(4)));

// ============== K1: bin edges into 1024 node-range buckets ================
// LDS ranking + in-LDS counting sort; block-level cursor atomics only.
// Packed edge: (src<<7)|(dst-base).
__global__ __launch_bounds__(256) void bucket_nr_kernel(
        const int* __restrict__ src,
        const int* __restrict__ dst,
        int* __restrict__ bcur,          // [NRB]
        int* __restrict__ bpk) {         // [NRB][RCAP]
    __shared__ int hist[NRB];
    __shared__ int lofs[NRB + 1];
    __shared__ int gbase[NRB];
    __shared__ int tsum[256];
    __shared__ int pk[K1CH * 4];         // 8KB
    int tid = threadIdx.x;
    for (int i = tid; i < NRB; i += 256) hist[i] = 0;
    __syncthreads();

    int c0 = blockIdx.x * K1CH;
    int bn_rk[K1IT][4], pkv[K1IT][4];
#pragma unroll
    for (int it = 0; it < K1IT; ++it) {
        int c = c0 + it * 256 + tid;
        if (c < N_EDGES / 4) {
            int4 s4 = ((const int4*)src)[c];
            int4 d4 = ((const int4*)dst)[c];
            int ss[4] = {s4.x, s4.y, s4.z, s4.w};
            int dd[4] = {d4.x, d4.y, d4.z, d4.w};
#pragma unroll
            for (int j = 0; j < 4; ++j) {
                int b = dd[j] / RW;
                int rk = atomicAdd(&hist[b], 1);
                bn_rk[it][j] = (b << 16) | rk;          // rk < 2048
                pkv[it][j] = (ss[j] << 7) | (dd[j] - b * RW);
            }
        } else {
#pragma unroll
            for (int j = 0; j < 4; ++j) bn_rk[it][j] = -1;
        }
    }
    __syncthreads();
    // block-wide exclusive scan of hist[1024] (4 entries/thread + ladder)
    int b4 = tid * 4;
    int h0 = hist[b4], h1 = hist[b4 + 1], h2 = hist[b4 + 2], h3 = hist[b4 + 3];
    int hs = h0 + h1 + h2 + h3;
    tsum[tid] = hs;
    __syncthreads();
    for (int d = 1; d < 256; d <<= 1) {
        int t = (tid >= d) ? tsum[tid - d] : 0;
        __syncthreads();
        tsum[tid] += t;
        __syncthreads();
    }
    int ex = tsum[tid] - hs;
    lofs[b4] = ex; lofs[b4 + 1] = ex + h0;
    lofs[b4 + 2] = ex + h0 + h1; lofs[b4 + 3] = ex + h0 + h1 + h2;
    if (tid == 255) lofs[NRB] = tsum[255];
    // global cursors (block-level, not per-edge)
    for (int b = tid; b < NRB; b += 256) {
        int cb = hist[b];
        gbase[b] = cb ? atomicAdd(&bcur[b], cb) : 0;
    }
    __syncthreads();
    // counting-sort into LDS
#pragma unroll
    for (int it = 0; it < K1IT; ++it)
#pragma unroll
        for (int j = 0; j < 4; ++j) {
            int br = bn_rk[it][j];
            if (br >= 0)
                pk[lofs[br >> 16] + (br & 0xffff)] = pkv[it][j];
        }
    __syncthreads();
    // coalesced flush (binary search for bucket of each position)
    int total = lofs[NRB];
    for (int i = tid; i < total; i += 256) {
        int lo = 0, hi = NRB;
        while (hi - lo > 1) {
            int mid = (lo + hi) >> 1;
            if (lofs[mid] <= i) lo = mid; else hi = mid;
        }
        int pos = gbase[lo] + (i - lofs[lo]);
        if (pos < RCAP) bpk[lo * RCAP + pos] = pk[i];
    }
}

// ============== K2: per-range histogram (plain stores, no memset) =========
__global__ __launch_bounds__(256) void hist_nr_kernel(
        const int* __restrict__ bcur,
        const int* __restrict__ bpk,
        int* __restrict__ cnt) {
    __shared__ int lh[RW];
    int r = blockIdx.x, tid = threadIdx.x;
    if (tid < RW) lh[tid] = 0;
    __syncthreads();
    int nb = min(bcur[r], RCAP);
    const int* p = bpk + r * RCAP;
    for (int i = tid; i < nb; i += 256)
        atomicAdd(&lh[p[i] & 127], 1);
    __syncthreads();
    int n = r * RW + tid;
    if (tid < RW && n < N_NODES) cnt[n] = lh[tid];
}

__global__ void scan_block_kernel(const int* __restrict__ cnt,
                                  int* __restrict__ ofs,
                                  int* __restrict__ partial) {
    __shared__ int s[256];
    int tid = threadIdx.x;
    int i = blockIdx.x * 256 + tid;
    int v = (i < N_NODES) ? ((cnt[i] + 7) & ~7) : 0;
    s[tid] = v;
    __syncthreads();
    for (int d = 1; d < 256; d <<= 1) {
        int t = (tid >= d) ? s[tid - d] : 0;
        __syncthreads();
        s[tid] += t;
        __syncthreads();
    }
    if (i < N_NODES) ofs[i] = s[tid] - v;
    if (tid == 255) partial[blockIdx.x] = s[255];
}

__global__ void scan_partials_kernel(int* __restrict__ partial, int nb) {
    __shared__ int s[512];
    int tid = threadIdx.x;
    int v = (tid < nb) ? partial[tid] : 0;
    s[tid] = v;
    __syncthreads();
    for (int d = 1; d < 512; d <<= 1) {
        int t = (tid >= d) ? s[tid - d] : 0;
        __syncthreads();
        s[tid] += t;
        __syncthreads();
    }
    if (tid < nb) partial[tid] = s[tid] - v;
}

__global__ void scan_add_kernel(int* __restrict__ ofs,
                                const int* __restrict__ partial,
                                const int* __restrict__ cnt,
                                int* __restrict__ esrc) {
    int i = blockIdx.x * 256 + threadIdx.x;
    if (i < N_NODES) {
        int o = ofs[i] + partial[blockIdx.x];
        ofs[i] = o;
        int c = cnt[i], p = (c + 7) & ~7;
        for (int j = c; j < p; ++j) esrc[o + j] = SENTINEL;
        if (i == N_NODES - 1) ofs[N_NODES] = o + p;
    }
}

// ============== K5: place edges (LDS cursors, plain stores) ===============
__global__ __launch_bounds__(256) void place_nr_kernel(
        const int* __restrict__ bcur,
        const int* __restrict__ bpk,
        const int* __restrict__ ofs,
        int* __restrict__ esrc) {
    __shared__ int lof[RW];
    __shared__ int lcur[RW];
    int r = blockIdx.x, tid = threadIdx.x;
    int n = r * RW + tid;
    if (tid < RW) {
        lof[tid] = (n < N_NODES) ? ofs[n] : 0;
        lcur[tid] = 0;
    }
    __syncthreads();
    int nb = min(bcur[r], RCAP);
    const int* p = bpk + r * RCAP;
    for (int i = tid; i < nb; i += 256) {
        int v = p[i];
        int dl = v & 127;
        int rk = atomicAdd(&lcur[dl], 1);
        esrc[lof[dl] + rk] = (unsigned)v >> 7;
    }
}

// --- Fallback CSR (round-10 path, if ws too small) ------------------------
__global__ __launch_bounds__(256) void hist_kernel(const int* __restrict__ dst,
                                                   int* __restrict__ cnt) {
    int g = blockIdx.x & (NXCD - 1);
    int lo = g * DRANGE, hi = lo + DRANGE;
    int t = (blockIdx.x >> 3) * 256 + threadIdx.x;
    const int NCH = N_EDGES / 4;
    const int STRIDE = (GRID / NXCD) * 256;
    for (int c = t; c < NCH; c += STRIDE) {
        int4 d4 = ((const int4*)dst)[c];
        if (d4.x >= lo && d4.x < hi) atomicAdd(&cnt[d4.x], 1);
        if (d4.y >= lo && d4.y < hi) atomicAdd(&cnt[d4.y], 1);
        if (d4.z >= lo && d4.z < hi) atomicAdd(&cnt[d4.z], 1);
        if (d4.w >= lo && d4.w < hi) atomicAdd(&cnt[d4.w], 1);
    }
}

__global__ __launch_bounds__(256) void scatter_edges_kernel(
        const int* __restrict__ src,
        const int* __restrict__ dst,
        const int* __restrict__ ofs,
        int* __restrict__ cnt,
        int* __restrict__ esrc) {
    int g = blockIdx.x & (NXCD - 1);
    int lo = g * DRANGE, hi = lo + DRANGE;
    int t = (blockIdx.x >> 3) * 256 + threadIdx.x;
    const int NCH = N_EDGES / 4;
    const int STRIDE = (GRID / NXCD) * 256;
    for (int c = t; c < NCH; c += STRIDE) {
        int4 s4 = ((const int4*)src)[c];
        int4 d4 = ((const int4*)dst)[c];
        if (d4.x >= lo && d4.x < hi) esrc[ofs[d4.x] + atomicSub(&cnt[d4.x], 1) - 1] = s4.x;
        if (d4.y >= lo && d4.y < hi) esrc[ofs[d4.y] + atomicSub(&cnt[d4.y], 1) - 1] = s4.y;
        if (d4.z >= lo && d4.z < hi) esrc[ofs[d4.z] + atomicSub(&cnt[d4.z], 1) - 1] = s4.z;
        if (d4.w >= lo && d4.w < hi) esrc[ofs[d4.w] + atomicSub(&cnt[d4.w], 1) - 1] = s4.w;
    }
}

// ====== Prep: x->fp16, W0..W2->fp16, zero sentinel rows (one kernel) ======
__global__ void prep_kernel(const float* __restrict__ x,
                            const float* __restrict__ W0,
                            const float* __restrict__ W1,
                            const float* __restrict__ W2,
                            __half* __restrict__ x16,
                            __half* __restrict__ w16,
                            __half* __restrict__ bufA,
                            __half* __restrict__ bufB) {
    int b = blockIdx.x;
    if (b < NB_CVT) {
        int i = b * 256 + threadIdx.x;
        float4 v = ((const float4*)x)[i];
        ((__half2*)x16)[2 * i + 0] = __floats2half2_rn(v.x, v.y);
        ((__half2*)x16)[2 * i + 1] = __floats2half2_rn(v.z, v.w);
    } else if (b < NB_CVT + 3) {
        int l = b - NB_CVT;
        const float* W = (l == 0) ? W0 : (l == 1) ? W1 : W2;
        for (int j = threadIdx.x; j < D * D; j += 256)
            w16[l * D * D + j] = __float2half(W[j]);
    } else {
        int tid = threadIdx.x;
        if (tid < 96) {
            __half* p = (tid < 32) ? x16 : (tid < 64) ? bufA : bufB;
            ((unsigned int*)(p + SENTINEL * D))[tid & 31] = 0u;
        }
    }
}

// ================= Gather: S[n] = h[n] + sum_neighbors h ==================
// Pure gather, no LDS, no barrier. Quarter-wave: 16 lanes/node, lane owns 4
// channels (uint2). Segments padded to 8 with sentinel (zero row).
// Sequential node order: esrc reads stream, h rows random (L2/L3-served).
__global__ __launch_bounds__(256) void gather_kernel(
        const __half* __restrict__ h_in,
        const int* __restrict__ ofs,
        const int* __restrict__ esrc,
        __half* __restrict__ s_out) {
    int w = threadIdx.x >> 6, lane = threadIdx.x & 63;
    int q = lane >> 4;
    int c4 = lane & 15;
    int n = blockIdx.x * 16 + w * 4 + q;
    const uint2* hp = (const uint2*)h_in;

    uint2 self = hp[n * 16 + c4];
    float2 sl = __half22float2(*(const __half2*)&self.x);
    float2 sh = __half22float2(*(const __half2*)&self.y);
    float a0 = sl.x, a1 = sl.y, a2 = sh.x, a3 = sh.y;

    int k = ofs[n], end = ofs[n + 1];
    for (; k < end; k += 8) {
        int4 i0 = *(const int4*)(esrc + k);
        int4 i1 = *(const int4*)(esrc + k + 4);
        uint2 r0 = hp[i0.x * 16 + c4];
        uint2 r1 = hp[i0.y * 16 + c4];
        uint2 r2 = hp[i0.z * 16 + c4];
        uint2 r3 = hp[i0.w * 16 + c4];
        uint2 r4 = hp[i1.x * 16 + c4];
        uint2 r5 = hp[i1.y * 16 + c4];
        uint2 r6 = hp[i1.z * 16 + c4];
        uint2 r7 = hp[i1.w * 16 + c4];
#define ACC(R) { float2 lo = __half22float2(*(const __half2*)&R.x); \
                 float2 hi = __half22float2(*(const __half2*)&R.y); \
                 a0 += lo.x; a1 += lo.y; a2 += hi.x; a3 += hi.y; }
        ACC(r0) ACC(r1) ACC(r2) ACC(r3) ACC(r4) ACC(r5) ACC(r6) ACC(r7)
#undef ACC
    }
    uint2 ov;
    *(__half2*)&ov.x = __floats2half2_rn(a0, a1);
    *(__half2*)&ov.y = __floats2half2_rn(a2, a3);
    ((uint2*)s_out)[n * 16 + c4] = ov;
}

// ================= MLP: h' = relu(S @ W) via MFMA =========================
__global__ __launch_bounds__(256) void mlp_kernel(
        const __half* __restrict__ S,
        const __half* __restrict__ W16,
        __half* __restrict__ h_out) {
    int w = threadIdx.x >> 6, lane = threadIdx.x & 63;
    int m = lane & 15;
    int kg = lane >> 4;
    const _Float16* Wp = (const _Float16*)W16;
    f16x8 bf[4][2];
#pragma unroll
    for (int ct = 0; ct < 4; ++ct)
#pragma unroll
        for (int kt = 0; kt < 2; ++kt)
#pragma unroll
            for (int j = 0; j < 8; ++j)
                bf[ct][kt][j] = Wp[(kt * 32 + kg * 8 + j) * D + ct * 16 + m];

    int t = blockIdx.x * 4 + w;
    if (t >= N_NODES / 16) return;
    const _Float16* Sp = (const _Float16*)S;
    int row = t * 16 + m;
    f16x8 a0 = *(const f16x8*)(Sp + row * D + kg * 8);
    f16x8 a1 = *(const f16x8*)(Sp + row * D + 32 + kg * 8);
    f32x4 c[4];
#pragma unroll
    for (int ct = 0; ct < 4; ++ct) {
        f32x4 z = {0.f, 0.f, 0.f, 0.f};
        z = __builtin_amdgcn_mfma_f32_16x16x32_f16(a0, bf[ct][0], z, 0, 0, 0);
        z = __builtin_amdgcn_mfma_f32_16x16x32_f16(a1, bf[ct][1], z, 0, 0, 0);
        c[ct] = z;
    }
#pragma unroll
    for (int ct = 0; ct < 4; ++ct)
#pragma unroll
        for (int r = 0; r < 4; ++r)
            h_out[(t * 16 + kg * 4 + r) * D + ct * 16 + m] =
                __float2half(fmaxf(c[ct][r], 0.f));
}

// ============ Final: L2-normalize + 64->16 linear (fp16 in) ===============
__global__ __launch_bounds__(256) void final_kernel(
        const __half* __restrict__ h,
        const float* __restrict__ W_out,
        const float* __restrict__ b_out,
        float* __restrict__ out,
        float* __restrict__ feat) {
    __shared__ float Wo[D][N_CLASSES];
    __shared__ float fs[4][2][D];
    int tid = threadIdx.x;
    for (int k = tid; k < D * N_CLASSES; k += 256)
        Wo[k >> 4][k & 15] = W_out[k];
    __syncthreads();
    int w = tid >> 6;
    int lane = tid & 63;
    int hh = lane >> 5;
    int c2 = lane & 31;
    const __half2* hp = (const __half2*)h;
    float bias = b_out[lane & 15];

    for (int g = blockIdx.x; g < NG8; g += GRID) {
        int n = g * 8 + w * 2 + hh;
        float2 v = __half22float2(hp[n * 32 + c2]);
        float ss = v.x * v.x + v.y * v.y;
#pragma unroll
        for (int off = 16; off; off >>= 1)
            ss += __shfl_xor(ss, off);
        float rinv = 1.f / fmaxf(sqrtf(ss), 1e-12f);
        float f0 = v.x * rinv, f1 = v.y * rinv;
        ((float2*)feat)[n * 32 + c2] = make_float2(f0, f1);
        fs[w][hh][2 * c2 + 0] = f0;
        fs[w][hh][2 * c2 + 1] = f1;
        if (c2 < N_CLASSES) {
            float acc = bias;
#pragma unroll
            for (int i = 0; i < D; ++i)
                acc = fmaf(fs[w][hh][i], Wo[i][c2], acc);
            out[n * N_CLASSES + c2] = acc;
        }
    }
}

// ==========================================================================
extern "C" void kernel_launch(void* const* d_in, const int* in_sizes, int n_in,
                              void* d_out, int out_size, void* d_ws, size_t ws_size,
                              hipStream_t stream) {
    const float* x     = (const float*)d_in[0];
    const int*   src   = (const int*)d_in[1];
    const int*   dst   = (const int*)d_in[2];
    const float* W0    = (const float*)d_in[3];
    const float* W1    = (const float*)d_in[4];
    const float* W2    = (const float*)d_in[5];
    const float* W_out = (const float*)d_in[6];
    const float* b_out = (const float*)d_in[7];

    float* out  = (float*)d_out;
    float* feat = (float*)d_out + (size_t)N_NODES * N_CLASSES;

    const int NB_NODE = (N_NODES + 255) / 256;       // 391
    const int NB_MLP  = (N_NODES / 16 + 3) / 4;      // 1563

    size_t off = 0;
    auto alloc = [&](size_t bytes) { size_t o = off; off = (off + bytes + 255) & ~(size_t)255; return o; };
    size_t o_cnt     = alloc((size_t)N_NODES * 4);
    size_t o_partial = alloc(512 * 4);
    size_t o_ofs     = alloc(((size_t)N_NODES + 1) * 4);
    size_t o_esrc    = alloc((size_t)ESRC_CAP * 4);
    size_t o_w16     = alloc((size_t)3 * D * D * 2);
    size_t o_X       = alloc((size_t)(N_NODES + 1) * D * 2);
    size_t o_A       = alloc((size_t)(N_NODES + 1) * D * 2);
    size_t o_B       = alloc((size_t)(N_NODES + 1) * D * 2);
    size_t o_bcur    = alloc((size_t)NRB * 4);
    size_t o_bpk     = alloc((size_t)NRB * RCAP * 4);    // 8.4MB
    size_t need_bkt  = off;

    char* w8 = (char*)d_ws;
    int*    cnt     = (int*)(w8 + o_cnt);
    int*    partial = (int*)(w8 + o_partial);
    int*    ofs     = (int*)(w8 + o_ofs);
    int*    esrc    = (int*)(w8 + o_esrc);
    __half* w16     = (__half*)(w8 + o_w16);
    __half* X       = (__half*)(w8 + o_X);
    __half* A       = (__half*)(w8 + o_A);
    __half* B       = (__half*)(w8 + o_B);

    if (ws_size >= need_bkt) {
        int* bcur = (int*)(w8 + o_bcur);
        int* bpk  = (int*)(w8 + o_bpk);
        hipMemsetAsync(bcur, 0, (size_t)NRB * 4, stream);
        bucket_nr_kernel<<<K1B, 256, 0, stream>>>(src, dst, bcur, bpk);
        hist_nr_kernel<<<NRB, 256, 0, stream>>>(bcur, bpk, cnt);
        scan_block_kernel<<<NB_NODE, 256, 0, stream>>>(cnt, ofs, partial);
        scan_partials_kernel<<<1, 512, 0, stream>>>(partial, NB_NODE);
        scan_add_kernel<<<NB_NODE, 256, 0, stream>>>(ofs, partial, cnt, esrc);
        place_nr_kernel<<<NRB, 256, 0, stream>>>(bcur, bpk, ofs, esrc);
    } else {
        hipMemsetAsync(cnt, 0, (size_t)N_NODES * 4, stream);
        hist_kernel<<<GRID, 256, 0, stream>>>(dst, cnt);
        scan_block_kernel<<<NB_NODE, 256, 0, stream>>>(cnt, ofs, partial);
        scan_partials_kernel<<<1, 512, 0, stream>>>(partial, NB_NODE);
        scan_add_kernel<<<NB_NODE, 256, 0, stream>>>(ofs, partial, cnt, esrc);
        scatter_edges_kernel<<<GRID, 256, 0, stream>>>(src, dst, ofs, cnt, esrc);
    }

    prep_kernel<<<NB_CVT + 4, 256, 0, stream>>>(x, W0, W1, W2, X, w16, A, B);

    gather_kernel<<<N_NODES / 16, 256, 0, stream>>>(X, ofs, esrc, A);
    mlp_kernel<<<NB_MLP, 256, 0, stream>>>(A, w16 + 0 * D * D, B);
    gather_kernel<<<N_NODES / 16, 256, 0, stream>>>(B, ofs, esrc, X);
    mlp_kernel<<<NB_MLP, 256, 0, stream>>>(X, w16 + 1 * D * D, A);
    gather_kernel<<<N_NODES / 16, 256, 0, stream>>>(A, ofs, esrc, B);
    mlp_kernel<<<NB_MLP, 256, 0, stream>>>(B, w16 + 2 * D * D, X);

    final_kernel<<<GRID, 256, 0, stream>>>(X, W_out, b_out, out, feat);
}